// Round 1
// baseline (800.647 us; speedup 1.0000x reference)
//
#include <hip/hip_runtime.h>
#include <math.h>

// MemContrastiveLoss on MI355X
// inputs: pred_obj_features f32 (8,16,16,256), memory f32 (8,16,256,16,256),
//         mem_table i32 (8,16,16)
// output: scalar f32 loss
//
// ws layout:
//   [0, 2MB)           preds_norm * (1/TEMP)   2048*256 f32
//   [2MB, 2MB+8KB)     denom                   2048 f32   (zeroed each launch)
//   [2MB+8KB, +8KB)    simpos (positive logit) 2048 f32   (always overwritten)

#define TEMP_INV 14.285714285714286f

__device__ __forceinline__ float wave_reduce_sum(float v) {
    #pragma unroll
    for (int off = 32; off; off >>= 1) v += __shfl_xor(v, off, 64);
    return v;
}

__global__ __launch_bounds__(256) void k_normalize_preds(
    const float* __restrict__ preds, float* __restrict__ out)
{
    // one wave per 256-float vector; 4 vectors per block
    int vec  = blockIdx.x * 4 + (threadIdx.x >> 6);
    int lane = threadIdx.x & 63;
    const float4* src = (const float4*)(preds + (size_t)vec * 256);
    float4 q = src[lane];
    float ss = q.x*q.x + q.y*q.y + q.z*q.z + q.w*q.w;
    ss = wave_reduce_sum(ss);
    float scale = TEMP_INV / fmaxf(sqrtf(ss), 1e-12f);
    float4 o;
    o.x = q.x * scale; o.y = q.y * scale; o.z = q.z * scale; o.w = q.w * scale;
    ((float4*)(out + (size_t)vec * 256))[lane] = o;
}

// grid = 128 (b,f) * 16 chunks; block = 256 threads; thread -> vector (m, j)
__global__ __launch_bounds__(256) void k_main(
    const float* __restrict__ mem, const int* __restrict__ table,
    const float* __restrict__ predsN,
    float* __restrict__ denom, float* __restrict__ simpos)
{
    int bf    = blockIdx.x >> 4;
    int chunk = blockIdx.x & 15;
    int t     = threadIdx.x;

    __shared__ int   s_cnt[16];
    __shared__ int   s_limit;
    __shared__ float s_den[16];

    if (t < 16) { s_cnt[t] = table[bf * 16 + t]; s_den[t] = 0.0f; }
    __syncthreads();
    if (t == 0) {
        int L = 1;
        #pragma unroll
        for (int i = 0; i < 16; ++i) L = max(L, s_cnt[i]);
        s_limit = L;
    }
    __syncthreads();
    int limit = s_limit;
    int m0 = chunk * 16;
    if (m0 >= limit) return;          // uniform per block; chunk 0 never exits (limit>=1)

    int m = m0 + (t >> 4);
    int j = t & 15;
    bool active = (m < limit);

    float acc[16];
    #pragma unroll
    for (int i = 0; i < 16; ++i) acc[i] = 0.0f;
    float ss = 0.0f;

    const float4* P = (const float4*)(predsN + (size_t)bf * 4096); // 16 rows x 64 quads
    if (active) {
        const float4* V = (const float4*)(mem + (size_t)bf * 1048576
                                              + (size_t)(m * 16 + j) * 256);
        #pragma unroll 2
        for (int q = 0; q < 64; ++q) {
            float4 v = V[q];
            ss = fmaf(v.x, v.x, fmaf(v.y, v.y, fmaf(v.z, v.z, fmaf(v.w, v.w, ss))));
            #pragma unroll
            for (int i = 0; i < 16; ++i) {
                float4 p = P[i * 64 + q];   // wave-uniform address -> scalar load
                acc[i] = fmaf(p.x, v.x, fmaf(p.y, v.y,
                         fmaf(p.z, v.z, fmaf(p.w, v.w, acc[i]))));
            }
        }
    }

    float scale = active ? (1.0f / fmaxf(sqrtf(ss), 1e-12f)) : 0.0f;

    #pragma unroll
    for (int i = 0; i < 16; ++i) {
        float logit = acc[i] * scale;
        bool valid = active &&
                     (((m < s_cnt[i]) && (j != i)) || ((m == 0) && (j == i)));
        float e = valid ? __expf(logit) : 0.0f;
        float s = wave_reduce_sum(e);
        if ((t & 63) == 0) atomicAdd(&s_den[i], s);
    }

    if (chunk == 0 && t < 16) {
        // thread t has (m=0, j=t): the positive for i=t
        simpos[bf * 16 + t] = acc[t] * scale;
    }
    __syncthreads();
    if (t < 16) atomicAdd(&denom[bf * 16 + t], s_den[t]);
}

__global__ __launch_bounds__(256) void k_loss(
    const float* __restrict__ denom, const float* __restrict__ simpos,
    float* __restrict__ out)
{
    __shared__ float s_part[4];
    int t = threadIdx.x;
    float sum = 0.0f;
    for (int it = t; it < 2048; it += 256) {
        float lp = simpos[it] - logf(denom[it]);
        float p  = __expf(lp);
        float om = 1.0f - p + 1e-12f;
        sum += -(om * om * logf(p + 1e-12f));
    }
    sum = wave_reduce_sum(sum);
    if ((t & 63) == 0) s_part[t >> 6] = sum;
    __syncthreads();
    if (t == 0)
        out[0] = (s_part[0] + s_part[1] + s_part[2] + s_part[3]) * (1.0f / 128.0f);
}

extern "C" void kernel_launch(void* const* d_in, const int* in_sizes, int n_in,
                              void* d_out, int out_size, void* d_ws, size_t ws_size,
                              hipStream_t stream) {
    (void)in_sizes; (void)n_in; (void)out_size; (void)ws_size;
    const float* preds  = (const float*)d_in[0];
    const float* memory = (const float*)d_in[1];
    const int*   table  = (const int*)d_in[2];
    float* out   = (float*)d_out;
    float* wsP   = (float*)d_ws;             // 2048*256 floats
    float* wsDen = wsP + 2048 * 256;         // 2048 floats
    float* wsPos = wsDen + 2048;             // 2048 floats

    hipMemsetAsync(wsDen, 0, 2048 * sizeof(float), stream);
    k_normalize_preds<<<512, 256, 0, stream>>>(preds, wsP);
    k_main<<<2048, 256, 0, stream>>>(memory, table, wsP, wsDen, wsPos);
    k_loss<<<1, 256, 0, stream>>>(wsDen, wsPos, out);
}